// Round 6
// baseline (182.628 us; speedup 1.0000x reference)
//
#include <hip/hip_runtime.h>

#define Bn 512
#define Tn 512
#define Cn 64

// Inputs (setup_inputs order):
// 0: emissions (B,T,C) f32   1: tags (B,T) i32   2: mask (B,T) i32
// 3: transitions (C,C) f32   4: start_transitions (C) f32   5: end_transitions (C) f32
// Output: scalar f32 = mean_b(log_denominator - log_numerator)
//
// R11: COOPERATIVE 2-WAVE CHAINS. Evidence from R5-R10: every 1-wave engine
// costs 800-1200 cy/step (~5.5-6 cy/instr effective) regardless of broadcast
// mechanism -> the serial per-wave instruction count is the wall. Fix: split
// each chain across 2 waves (128-thread block):
//   - wave w owns output states [32w,32w+32); lane pair (l, l^32) splits the
//     64-term dot into 32-term halves, combined by one shfl_xor(32).
//   - alpha exchanged via 512B LDS ping-pong; read back as 8 uniform
//     ds_read_b128 broadcasts (replaces 64 readlanes entirely).
//   - renorm every 4th step takes its max FROM THE BROADCAST REGS (already
//     loaded for the dot) + one cross-half shfl: global max, zero extra sync.
//     Deferred-scale semantics identical to the validated R5/R9 lineage.
//   - 2 waves/SIMD occupancy: independent chains hide each other's LDS and
//     issue latency (what killed the 1-wave LDS engine in R6).

typedef float f4 __attribute__((ext_vector_type(4)));

template <int CTRL>
__device__ __forceinline__ float fmax_dpp(const float v) {
    const int o = __builtin_amdgcn_update_dpp(__float_as_int(v), __float_as_int(v),
                                              CTRL, 0xF, 0xF, false);
    return fmaxf(v, __int_as_float(o));
}

// Validated wave64 max -> lane 63, readlane-broadcast.
__device__ __forceinline__ float wave_max64(float v) {
    v = fmax_dpp<0x0B1>(v);
    v = fmax_dpp<0x04E>(v);
    v = fmax_dpp<0x141>(v);
    v = fmax_dpp<0x140>(v);
    v = fmax_dpp<0x142>(v);
    v = fmax_dpp<0x143>(v);
    return __int_as_float(__builtin_amdgcn_readlane(__float_as_int(v), 63));
}

// Load 8 x f4 broadcast values (this lane's 32 terms) from the ping buffer.
#define READ_BC(rb)                                                        \
    const f4* ap_ = (const f4*)(&abuf[(rb)][h << 5]);                      \
    const f4 b0_ = ap_[0], b1_ = ap_[1], b2_ = ap_[2], b3_ = ap_[3],       \
             b4_ = ap_[4], b5_ = ap_[5], b6_ = ap_[6], b7_ = ap_[7];

// Half-max (this lane's 32 broadcast values) from the broadcast regs.
#define MAX_FROM_BC(dst)                                                   \
    float dst;                                                             \
    {                                                                      \
        f4 t0_ = __builtin_elementwise_max(b0_, b1_);                      \
        f4 t1_ = __builtin_elementwise_max(b2_, b3_);                      \
        f4 t2_ = __builtin_elementwise_max(b4_, b5_);                      \
        f4 t3_ = __builtin_elementwise_max(b6_, b7_);                      \
        t0_ = __builtin_elementwise_max(t0_, t1_);                         \
        t2_ = __builtin_elementwise_max(t2_, t3_);                         \
        t0_ = __builtin_elementwise_max(t0_, t2_);                         \
        dst = fmaxf(fmaxf(t0_.x, t0_.y), fmaxf(t0_.z, t0_.w));             \
    }

// 32-term partial dot: broadcast regs x wreg[0..31], 4 accumulator chains.
#define DOT_FROM_BC(dst)                                                   \
    float dst;                                                             \
    {                                                                      \
        float a0_ = b0_.x * wreg[0],  a1_ = b0_.y * wreg[1];               \
        float a2_ = b0_.z * wreg[2],  a3_ = b0_.w * wreg[3];               \
        a0_ = fmaf(b1_.x, wreg[4],  a0_); a1_ = fmaf(b1_.y, wreg[5],  a1_);\
        a2_ = fmaf(b1_.z, wreg[6],  a2_); a3_ = fmaf(b1_.w, wreg[7],  a3_);\
        a0_ = fmaf(b2_.x, wreg[8],  a0_); a1_ = fmaf(b2_.y, wreg[9],  a1_);\
        a2_ = fmaf(b2_.z, wreg[10], a2_); a3_ = fmaf(b2_.w, wreg[11], a3_);\
        a0_ = fmaf(b3_.x, wreg[12], a0_); a1_ = fmaf(b3_.y, wreg[13], a1_);\
        a2_ = fmaf(b3_.z, wreg[14], a2_); a3_ = fmaf(b3_.w, wreg[15], a3_);\
        a0_ = fmaf(b4_.x, wreg[16], a0_); a1_ = fmaf(b4_.y, wreg[17], a1_);\
        a2_ = fmaf(b4_.z, wreg[18], a2_); a3_ = fmaf(b4_.w, wreg[19], a3_);\
        a0_ = fmaf(b5_.x, wreg[20], a0_); a1_ = fmaf(b5_.y, wreg[21], a1_);\
        a2_ = fmaf(b5_.z, wreg[22], a2_); a3_ = fmaf(b5_.w, wreg[23], a3_);\
        a0_ = fmaf(b6_.x, wreg[24], a0_); a1_ = fmaf(b6_.y, wreg[25], a1_);\
        a2_ = fmaf(b6_.z, wreg[26], a2_); a3_ = fmaf(b6_.w, wreg[27], a3_);\
        a0_ = fmaf(b7_.x, wreg[28], a0_); a1_ = fmaf(b7_.y, wreg[29], a1_);\
        a2_ = fmaf(b7_.z, wreg[30], a2_); a3_ = fmaf(b7_.w, wreg[31], a3_);\
        dst = (a0_ + a1_) + (a2_ + a3_);                                   \
    }

// blocks 0..511: forward chain bt (steps t=1..256) + numerator.
// blocks 512..1023: backward chain bt (factors u=511..257, 255 steps).
// 128 threads = 2 waves per chain.
__global__ __launch_bounds__(128) void crf_half_kernel(
    const float* __restrict__ emissions,
    const int*   __restrict__ tags,
    const int*   __restrict__ mask,
    const float* __restrict__ transitions,
    const float* __restrict__ start_t,
    const float* __restrict__ end_t,
    float*       __restrict__ ws_alpha,   // [Bn][Cn]
    float*       __restrict__ ws_beta,    // [Bn][Cn]
    float*       __restrict__ ws_lsF,     // [Bn]
    float*       __restrict__ ws_lsB,     // [Bn]
    float*       __restrict__ ws_num,     // [Bn]
    float*       __restrict__ out)
{
    const int  blk  = blockIdx.x;
    const bool fwd  = blk < Bn;
    const int  bt   = blk & (Bn - 1);
    const int  tid  = threadIdx.x;
    const int  wv   = tid >> 6;            // wave 0/1
    const int  l    = tid & 63;            // lane
    const int  h    = l >> 5;              // term-half: 0 -> i in [0,32), 1 -> [32,64)
    const int  ownj = (wv << 5) | (l & 31);// owned output state (duplicated in lane pair)

    if (blk == 0 && tid == 0) out[0] = 0.f;

    __shared__ __align__(16) float abuf[2][Cn];   // alpha/gamma ping-pong

    const float* em  = emissions + (size_t)bt * Tn * Cn + ownj;
    const float* em0 = emissions + (size_t)bt * Tn * Cn;
    const int*   mk  = mask + bt * Tn;
    const int*   tg  = tags + bt * Tn;

    // Per-lane 32 weights: fwd lane needs column ownj rows [32h,32h+32);
    // bwd lane needs row ownj cols [32h,32h+32).
    float wreg[32];
    if (fwd) {
#pragma unroll
        for (int m = 0; m < 32; ++m)
            wreg[m] = __expf(transitions[(h * 32 + m) * Cn + ownj]);
    } else {
#pragma unroll
        for (int m = 0; m < 32; ++m)
            wreg[m] = __expf(transitions[ownj * Cn + h * 32 + m]);
    }

    float log_scale, self;

    if (fwd) {
        // t = 0 init: global max over all 64 states (each wave computes it
        // over state=l, so wave_max64 is already global; both waves agree).
        const float lp_l = start_t[l] + em0[l];
        const float m0   = wave_max64(lp_l);
        log_scale = m0;
        self = __expf(start_t[ownj] + em0[ownj] - m0);

        abuf[0][ownj] = self;              // duplicated-lane same-value write
        __syncthreads();

        float cE[4]; int cM[4];
#pragma unroll
        for (int k = 0; k < 4; ++k) { cE[k] = em[(size_t)(1 + k) * Cn]; cM[k] = mk[1 + k]; }

#pragma unroll 1
        for (int g = 0; g < 64; ++g) {     // 64 groups x 4 = 256 steps
            float nE[4]; int nM[4];
#pragma unroll
            for (int k = 0; k < 4; ++k) {
                const int t = 4 * g + 5 + k;           // <= 260 < Tn
                nE[k] = em[(size_t)t * Cn]; nM[k] = mk[t];
            }
            float ex[4];
#pragma unroll
            for (int k = 0; k < 4; ++k) ex[k] = __expf(cE[k]);

#pragma unroll
            for (int k = 0; k < 4; ++k) {
                const int rb = k & 1;       // step parity (4 | group base)
                READ_BC(rb);
                float c_ = 1.0f;
                if (k == 0 && g > 0) {      // renorm from broadcast regs (t=4g values)
                    MAX_FROM_BC(mxl_);
                    const float mx_ = fmaxf(mxl_, __shfl_xor(mxl_, 32, 64));
                    c_ = __builtin_amdgcn_rcpf(mx_);
                    log_scale += __logf(mx_);
                }
                DOT_FROM_BC(part_);
                float s = (part_ + __shfl_xor(part_, 32, 64)) * ex[k];
                if (!cM[k]) s = self;       // frozen step: alpha carries
                if (k == 0) s *= c_;        // deferred scale (validated order)
                self = s;
                abuf[rb ^ 1][ownj] = s;
                __syncthreads();
            }
#pragma unroll
            for (int k = 0; k < 4; ++k) { cE[k] = nE[k]; cM[k] = nM[k]; }
        }

        if (l < 32) ws_alpha[bt * Cn + ownj] = self;   // alpha_256 (scaled)

        // ---- numerator AFTER the serial loop (wave 0 only) ----
        if (wv == 0) {
            float nsum = 0.f; int mcnt = 0;
            for (int t = l; t < Tn; t += 64) {
                const int tag_t = tg[t];
                const int m_t   = mk[t];
                mcnt += m_t;
                if (t >= 1 && m_t)
                    nsum += transitions[tg[t - 1] * Cn + tag_t] + em0[t * Cn + tag_t];
            }
#pragma unroll
            for (int off = 32; off > 0; off >>= 1) {
                nsum += __shfl_xor(nsum, off, 64);
                mcnt += __shfl_xor(mcnt, off, 64);
            }
            if (l == 0) {
                ws_lsF[bt] = log_scale;
                const int t0 = tg[0];
                const int tl = tg[mcnt - 1];
                ws_num[bt] = start_t[t0] + em0[t0] + nsum + end_t[tl];
            }
        }
    } else {
        // beta_511 init.
        const float lp_l = end_t[l];
        const float m0   = wave_max64(lp_l);
        log_scale = m0;
        self = __expf(end_t[ownj] - m0);

        // e pipeline: exC = exp for current group; eN = loaded e for group+1.
        float eN[4], exC[4]; int mC[4], mN[4];
#pragma unroll
        for (int k = 0; k < 4; ++k) {
            exC[k] = __expf(em[(size_t)(Tn - 1 - k) * Cn]);   // group 0: u=511..508
            eN[k]  = em[(size_t)(Tn - 5 - k) * Cn];           // group 1: u=507..504
            mC[k]  = mk[Tn - 1 - k];
            mN[k]  = mk[Tn - 5 - k];
        }

        abuf[0][ownj] = self * exC[0];     // gamma for step 0 (u=511)
        __syncthreads();

#pragma unroll 1
        for (int g = 0; g < 64; ++g) {     // steps s = 4g+k, active while s < 255
            float eF[4]; int mF[4];
#pragma unroll
            for (int k = 0; k < 4; ++k) {
                const int u = 503 - 4 * g - k;                // >= 248 >= 0
                eF[k] = em[(size_t)u * Cn]; mF[k] = mk[u];
            }
            float exN[4];
#pragma unroll
            for (int k = 0; k < 4; ++k) exN[k] = __expf(eN[k]);

#pragma unroll
            for (int k = 0; k < 4; ++k) {
                const int sidx = 4 * g + k;
                if (sidx < Tn / 2 - 1) {   // 255 steps; skip only g=63,k=3
                    const int rb = k & 1;
                    READ_BC(rb);
                    float c_ = 1.0f;
                    if (k == 0 && g > 0) {  // renorm on published gamma (exact reformulation)
                        MAX_FROM_BC(mxl_);
                        const float mx_ = fmaxf(mxl_, __shfl_xor(mxl_, 32, 64));
                        c_ = __builtin_amdgcn_rcpf(mx_);
                        log_scale += __logf(mx_);
                    }
                    DOT_FROM_BC(part_);
                    float s = part_ + __shfl_xor(part_, 32, 64);
                    if (!mC[k]) s = self;   // frozen step: beta carries
                    if (k == 0) s *= c_;
                    self = s;
                    const float exn = (k < 3) ? exC[k + 1] : exN[0]; // e for step s+1
                    abuf[rb ^ 1][ownj] = s * exn;
                    __syncthreads();
                }
            }
#pragma unroll
            for (int k = 0; k < 4; ++k) {
                exC[k] = exN[k]; eN[k] = eF[k]; mC[k] = mN[k]; mN[k] = mF[k];
            }
        }

        if (l < 32) ws_beta[bt * Cn + ownj] = self;    // beta_256 (scaled)
        if (tid == 0) ws_lsB[bt] = log_scale;
    }
}

#undef READ_BC
#undef MAX_FROM_BC
#undef DOT_FROM_BC

// Per chain: denom = lsF + lsB + log(sum_i alpha[i]*beta[i]); mean-reduce.
// 32 blocks x 16 waves; one chain per wave; one atomicAdd per block.
__global__ __launch_bounds__(1024) void crf_combine_kernel(
    const float* __restrict__ ws_alpha,
    const float* __restrict__ ws_beta,
    const float* __restrict__ ws_lsF,
    const float* __restrict__ ws_lsB,
    const float* __restrict__ ws_num,
    float*       __restrict__ out)
{
    const int wv = threadIdx.x >> 6;          // wave 0..15
    const int j  = threadIdx.x & 63;
    const int bt = blockIdx.x * 16 + wv;

    __shared__ float part[16];

    float v = ws_alpha[bt * Cn + j] * ws_beta[bt * Cn + j];
#pragma unroll
    for (int off = 32; off > 0; off >>= 1) v += __shfl_xor(v, off, 64);
    if (j == 0) {
        part[wv] = ws_lsF[bt] + ws_lsB[bt] + __logf(v) - ws_num[bt];
    }
    __syncthreads();
    if (threadIdx.x < 64) {
        float p = (j < 16) ? part[j] : 0.f;
#pragma unroll
        for (int off = 32; off > 0; off >>= 1) p += __shfl_xor(p, off, 64);
        if (j == 0) atomicAdd(out, p * (1.0f / Bn));
    }
}

extern "C" void kernel_launch(void* const* d_in, const int* in_sizes, int n_in,
                              void* d_out, int out_size, void* d_ws, size_t ws_size,
                              hipStream_t stream)
{
    const float* emissions   = (const float*)d_in[0];
    const int*   tags        = (const int*)d_in[1];
    const int*   mask        = (const int*)d_in[2];
    const float* transitions = (const float*)d_in[3];
    const float* start_t     = (const float*)d_in[4];
    const float* end_t       = (const float*)d_in[5];

    float* ws       = (float*)d_ws;
    float* ws_alpha = ws;                       // 512*64
    float* ws_beta  = ws_alpha + Bn * Cn;       // 512*64
    float* ws_lsF   = ws_beta + Bn * Cn;        // 512
    float* ws_lsB   = ws_lsF + Bn;              // 512
    float* ws_num   = ws_lsB + Bn;              // 512

    crf_half_kernel<<<2 * Bn, 128, 0, stream>>>(emissions, tags, mask, transitions,
                                                start_t, end_t,
                                                ws_alpha, ws_beta, ws_lsF, ws_lsB, ws_num,
                                                (float*)d_out);
    crf_combine_kernel<<<Bn / 16, 1024, 0, stream>>>(ws_alpha, ws_beta, ws_lsF, ws_lsB,
                                                     ws_num, (float*)d_out);
}